// Round 2
// baseline (554.984 us; speedup 1.0000x reference)
//
#include <hip/hip_runtime.h>
#include <hip/hip_bf16.h>

#define B_ 32
#define S_ 2048
#define D_ 512

typedef __attribute__((ext_vector_type(8))) short bf16x8;   // 8 bf16 = 4 VGPRs
typedef __attribute__((ext_vector_type(4))) float f32x4;    // MFMA 16x16 accumulator
typedef unsigned short ushort_t;

__device__ __forceinline__ float b2f(ushort_t u) {
  union { unsigned int i; float f; } v; v.i = ((unsigned int)u) << 16; return v.f;
}
__device__ __forceinline__ ushort_t f2b(float f) {   // RTNE fp32 -> bf16 bits
  union { float f; unsigned int i; } v; v.f = f;
  return (ushort_t)((v.i + 0x7FFFu + ((v.i >> 16) & 1u)) >> 16);
}

__device__ __forceinline__ f32x4 mfma16(bf16x8 a, bf16x8 b, f32x4 c) {
  return __builtin_amdgcn_mfma_f32_16x16x32_bf16(a, b, c, 0, 0, 0);
}

// ---------------------------------------------------------------------------
// dtype detection: for a bf16 array the LOW half of each 32-bit word is a real
// bf16 value (exponent ~[117,129] for N(0,1) data); for an fp32 array it is
// mantissa bits (exponent ~uniform, ~12% in range). flag: 1 = bf16, 0 = fp32.
// ---------------------------------------------------------------------------
__global__ void detect_kernel(const unsigned int* __restrict__ w, int* __restrict__ flag) {
  __shared__ int cnt;
  if (threadIdx.x == 0) cnt = 0;
  __syncthreads();
  int c = 0;
  #pragma unroll
  for (int i = 0; i < 4; ++i) {
    unsigned int v = w[threadIdx.x + i * 256];
    unsigned int e = (v >> 7) & 0xFFu;          // exponent of low half as bf16
    if (e >= 110u && e <= 140u) ++c;
  }
  atomicAdd(&cnt, c);
  __syncthreads();
  if (threadIdx.x == 0) flag[0] = (cnt > 512) ? 1 : 0;
}

// Load one element as float, DT=0: fp32 storage, DT=1: bf16 storage.
template <int DT>
__device__ __forceinline__ float ldf(const void* p, size_t idx) {
  if constexpr (DT == 0) return ((const float*)p)[idx];
  else                   return b2f(((const ushort_t*)p)[idx]);
}

// Stage a [128 x 32] bf16 tile into LDS from row-major source (row stride D_).
// 256 threads: thread t handles row t>>1, 16 elements (half = t&1).
// Chunk c (8 k-elements) of row r is stored at slot c ^ ((r>>1)&3) so that
// read_frag's b128 reads spread across bank granules.
template <int DT>
__device__ __forceinline__ void stage_tile(const void* gv, size_t elem_off,
                                           ushort_t* tile, int tid) {
  const int row = tid >> 1, half = tid & 1;
  const size_t base = elem_off + (size_t)row * D_ + half * 16;
  bf16x8 ch0, ch1;
  if constexpr (DT == 0) {
    const float4* src = (const float4*)((const float*)gv + base);
    float4 a = src[0], b = src[1], c = src[2], d = src[3];
    ushort_t t[16];
    t[0] = f2b(a.x); t[1] = f2b(a.y); t[2]  = f2b(a.z); t[3]  = f2b(a.w);
    t[4] = f2b(b.x); t[5] = f2b(b.y); t[6]  = f2b(b.z); t[7]  = f2b(b.w);
    t[8] = f2b(c.x); t[9] = f2b(c.y); t[10] = f2b(c.z); t[11] = f2b(c.w);
    t[12] = f2b(d.x); t[13] = f2b(d.y); t[14] = f2b(d.z); t[15] = f2b(d.w);
    ch0 = *(const bf16x8*)t; ch1 = *(const bf16x8*)(t + 8);
  } else {
    const bf16x8* src = (const bf16x8*)((const ushort_t*)gv + base);
    ch0 = src[0]; ch1 = src[1];
  }
  const int swz = (row >> 1) & 3;
  const int c0 = half * 2, c1 = c0 + 1;
  *(bf16x8*)(tile + row * 32 + ((c0 ^ swz) << 3)) = ch0;
  *(bf16x8*)(tile + row * 32 + ((c1 ^ swz) << 3)) = ch1;
}

// read one 8-element (K=32) MFMA fragment; row = tile-local m (or n), quad = lane>>4
__device__ __forceinline__ bf16x8 read_frag(const ushort_t* tile, int row, int quad) {
  int g = quad ^ ((row >> 1) & 3);
  return *(const bf16x8*)(tile + row * 32 + g * 8);
}

// ---------------------------------------------------------------------------
// Kernel 1: gate[b,s] = sigmoid( sum_e (relu(old_x@W1^T + b1) + old_x)*W2 + b2 )
// ---------------------------------------------------------------------------
template <int DT>
__global__ __launch_bounds__(256, 2)
void gate_kernel(const void* __restrict__ old_x, const int* __restrict__ lang,
                 const void* __restrict__ W1, const void* __restrict__ b1,
                 const void* __restrict__ W2, const void* __restrict__ b2,
                 const int* __restrict__ flag, float* __restrict__ gate) {
  if (flag[0] != DT) return;
  const int b    = blockIdx.y;
  const int s0   = blockIdx.x * 128;
  const int tid  = threadIdx.x;
  const int wave = tid >> 6, lane = tid & 63, quad = lane >> 4, ln = lane & 15;
  const int m_off = (wave >> 1) * 64, n_off = (wave & 1) * 64;
  const int lg = lang[b];

  __shared__ __align__(16) ushort_t As[128 * 32];
  __shared__ __align__(16) ushort_t Bs[128 * 32];
  __shared__ float b1s[512], w2s[512], logit[128];

  for (int i = tid; i < 512; i += 256) {
    b1s[i] = ldf<DT>(b1, (size_t)lg * 512 + i);
    w2s[i] = ldf<DT>(W2, (size_t)lg * 512 + i);
  }
  if (tid < 128) logit[tid] = 0.f;
  __syncthreads();

  // residual term: sum_e old_x[s,e]*W2[e]  (2 threads per row, 256 e each)
  {
    const int row = tid >> 1, half = tid & 1;
    const size_t off = ((size_t)b * S_ + s0 + row) * D_ + half * 256;
    float ex = 0.f;
    if constexpr (DT == 0) {
      const float4* xr = (const float4*)((const float*)old_x + off);
      #pragma unroll 8
      for (int c = 0; c < 64; ++c) {
        float4 v = xr[c];
        const float* wp = &w2s[half * 256 + c * 4];
        ex += v.x * wp[0] + v.y * wp[1] + v.z * wp[2] + v.w * wp[3];
      }
    } else {
      const ushort_t* xr = (const ushort_t*)old_x + off;
      #pragma unroll 4
      for (int c = 0; c < 32; ++c) {
        bf16x8 v = *(const bf16x8*)(xr + c * 8);
        #pragma unroll
        for (int j = 0; j < 8; ++j)
          ex += b2f((ushort_t)v[j]) * w2s[half * 256 + c * 8 + j];
      }
    }
    atomicAdd(&logit[row], ex);
  }

  const size_t Aoff = ((size_t)b * S_ + s0) * D_;
  float logacc[16];
  #pragma unroll
  for (int i = 0; i < 16; ++i) logacc[i] = 0.f;

  for (int et = 0; et < 4; ++et) {
    const int e0 = et * 128;
    const size_t Boff = ((size_t)lg * D_ + e0) * D_;
    f32x4 acc[16];
    #pragma unroll
    for (int i = 0; i < 16; ++i) { f32x4 z = {0.f, 0.f, 0.f, 0.f}; acc[i] = z; }

    for (int k0 = 0; k0 < D_; k0 += 32) {
      __syncthreads();
      stage_tile<DT>(old_x, Aoff + k0, As, tid);
      stage_tile<DT>(W1,   Boff + k0, Bs, tid);
      __syncthreads();
      bf16x8 af[4], bfr[4];
      #pragma unroll
      for (int mf = 0; mf < 4; ++mf) af[mf]  = read_frag(As, m_off + mf * 16 + ln, quad);
      #pragma unroll
      for (int nf = 0; nf < 4; ++nf) bfr[nf] = read_frag(Bs, n_off + nf * 16 + ln, quad);
      #pragma unroll
      for (int mf = 0; mf < 4; ++mf)
        #pragma unroll
        for (int nf = 0; nf < 4; ++nf)
          acc[mf * 4 + nf] = mfma16(af[mf], bfr[nf], acc[mf * 4 + nf]);
    }
    // fused epilogue: relu(acc+b1)*W2, accumulate per-row partials
    #pragma unroll
    for (int nf = 0; nf < 4; ++nf) {
      int e = e0 + n_off + nf * 16 + ln;
      float b1v = b1s[e], w2v = w2s[e];
      #pragma unroll
      for (int mf = 0; mf < 4; ++mf)
        #pragma unroll
        for (int r = 0; r < 4; ++r) {
          float v = acc[mf * 4 + nf][r] + b1v;
          logacc[mf * 4 + r] += fmaxf(v, 0.f) * w2v;
        }
    }
  }

  // sum across the 16 e-columns held by lanes sharing a quad
  #pragma unroll
  for (int off = 1; off < 16; off <<= 1)
    #pragma unroll
    for (int i = 0; i < 16; ++i)
      logacc[i] += __shfl_xor(logacc[i], off, 64);
  if (ln == 0) {
    #pragma unroll
    for (int mf = 0; mf < 4; ++mf)
      #pragma unroll
      for (int r = 0; r < 4; ++r)
        atomicAdd(&logit[m_off + mf * 16 + quad * 4 + r], logacc[mf * 4 + r]);
  }
  __syncthreads();
  if (tid < 128) {
    float b2v = ldf<DT>(b2, lg);
    float l = logit[tid] + b2v;
    gate[(size_t)b * S_ + s0 + tid] = 1.f / (1.f + expf(-l));
  }
}

// ---------------------------------------------------------------------------
// Kernel 2: out = (1-g)*x@share_W^T + g*x@langs_W[lang]^T
// ---------------------------------------------------------------------------
template <int DT>
__global__ __launch_bounds__(256, 2)
void out_kernel(const void* __restrict__ x, const int* __restrict__ lang,
                const void* __restrict__ shareW, const void* __restrict__ langsW,
                const float* __restrict__ gate, const int* __restrict__ flag,
                void* __restrict__ out) {
  if (flag[0] != DT) return;
  const int b    = blockIdx.z;
  const int s0   = blockIdx.y * 128;
  const int e0   = blockIdx.x * 128;
  const int tid  = threadIdx.x;
  const int wave = tid >> 6, lane = tid & 63, quad = lane >> 4, ln = lane & 15;
  const int m_off = (wave >> 1) * 64, n_off = (wave & 1) * 64;
  const int lg = lang[b];

  __shared__ __align__(16) ushort_t As[128 * 32];
  __shared__ __align__(16) ushort_t Ss[128 * 32];
  __shared__ __align__(16) ushort_t Ls[128 * 32];

  const size_t Aoff = ((size_t)b * S_ + s0) * D_;
  const size_t Soff = (size_t)e0 * D_;
  const size_t Loff = ((size_t)lg * D_ + e0) * D_;

  f32x4 accS[16], accL[16];
  #pragma unroll
  for (int i = 0; i < 16; ++i) {
    f32x4 z = {0.f, 0.f, 0.f, 0.f};
    accS[i] = z; accL[i] = z;
  }

  for (int k0 = 0; k0 < D_; k0 += 32) {
    __syncthreads();
    stage_tile<DT>(x,      Aoff + k0, As, tid);
    stage_tile<DT>(shareW, Soff + k0, Ss, tid);
    stage_tile<DT>(langsW, Loff + k0, Ls, tid);
    __syncthreads();
    bf16x8 af[4], sf[4], lf[4];
    #pragma unroll
    for (int mf = 0; mf < 4; ++mf) af[mf] = read_frag(As, m_off + mf * 16 + ln, quad);
    #pragma unroll
    for (int nf = 0; nf < 4; ++nf) {
      sf[nf] = read_frag(Ss, n_off + nf * 16 + ln, quad);
      lf[nf] = read_frag(Ls, n_off + nf * 16 + ln, quad);
    }
    #pragma unroll
    for (int mf = 0; mf < 4; ++mf)
      #pragma unroll
      for (int nf = 0; nf < 4; ++nf) {
        accS[mf * 4 + nf] = mfma16(af[mf], sf[nf], accS[mf * 4 + nf]);
        accL[mf * 4 + nf] = mfma16(af[mf], lf[nf], accL[mf * 4 + nf]);
      }
  }

  // epilogue: blend with gate, store (fp32 or bf16 to match storage dtype)
  #pragma unroll
  for (int mf = 0; mf < 4; ++mf) {
    int srow = s0 + m_off + mf * 16 + quad * 4;
    float gv[4];
    #pragma unroll
    for (int r = 0; r < 4; ++r) gv[r] = gate[(size_t)b * S_ + srow + r];
    #pragma unroll
    for (int nf = 0; nf < 4; ++nf) {
      int col = e0 + n_off + nf * 16 + ln;
      f32x4 cs = accS[mf * 4 + nf], cl = accL[mf * 4 + nf];
      #pragma unroll
      for (int r = 0; r < 4; ++r) {
        float v = cs[r] + gv[r] * (cl[r] - cs[r]);
        size_t idx = ((size_t)b * S_ + srow + r) * D_ + col;
        if constexpr (DT == 0) ((float*)out)[idx] = v;
        else                   ((ushort_t*)out)[idx] = f2b(v);
      }
    }
  }
}

extern "C" void kernel_launch(void* const* d_in, const int* in_sizes, int n_in,
                              void* d_out, int out_size, void* d_ws, size_t ws_size,
                              hipStream_t stream) {
  const void* old_x  = d_in[0];
  const void* x      = d_in[1];
  const int*  lang   = (const int*)d_in[2];
  const void* shareW = d_in[3];
  const void* langsW = d_in[4];
  const void* gW1    = d_in[5];
  const void* gb1    = d_in[6];
  const void* gW2    = d_in[7];
  const void* gb2    = d_in[8];

  float* gate = (float*)d_ws;                                   // B*S floats
  int*   flag = (int*)((char*)d_ws + (size_t)B_ * S_ * sizeof(float));

  detect_kernel<<<1, 256, 0, stream>>>((const unsigned int*)old_x, flag);

  dim3 g1(S_ / 128, B_);
  gate_kernel<0><<<g1, dim3(256), 0, stream>>>(old_x, lang, gW1, gb1, gW2, gb2, flag, gate);
  gate_kernel<1><<<g1, dim3(256), 0, stream>>>(old_x, lang, gW1, gb1, gW2, gb2, flag, gate);

  dim3 g2(D_ / 128, S_ / 128, B_);
  out_kernel<0><<<g2, dim3(256), 0, stream>>>(x, lang, shareW, langsW, gate, flag, d_out);
  out_kernel<1><<<g2, dim3(256), 0, stream>>>(x, lang, shareW, langsW, gate, flag, d_out);
}